// Round 1
// baseline (1868.710 us; speedup 1.0000x reference)
//
#include <hip/hip_runtime.h>
#include <math.h>

#define VOXN 32768

// ---- workspace layout (float offsets) ----
constexpr int OFF_STATS_Y   = 0;        // 512  (sum[256], sumsq[256])
constexpr int OFF_STATS_X2P = 512;      // 256  (sum[128], sumsq[128])
constexpr int OFF_STATS_H   = 768;      // 512  (sum[256], sumsq[256])
constexpr int OFF_PVOL      = 1280;     // 46656 padded 36^3 volume
constexpr int OFF_TPAR      = 48000;    // 1024*32 words (int+float mixed)
constexpr int OFF_W1T       = 80768;    // 65536: w1t[g][c][o] = w1[g][o][c]
constexpr int OFF_W2T       = 146304;   // 32768: w2t[c][o]
constexpr int OFF_W3AT      = 179072;   // 4096
constexpr int OFF_W3BT      = 183168;   // 5120
constexpr int OFF_W3CT      = 188288;   // 6144
constexpr int OFF_W3DT      = 194432;   // 7168
constexpr int OFF_W4T       = 201600;   // 2048
constexpr int OFF_YH        = 203648;   // 8388608 (y, later reused as H)
constexpr int OFF_X2P       = 8592256;  // 4194304
// total = 12786560 floats = 51.1 MB

// ---------------- S0: setup ----------------
__global__ void s0_setup(const float* __restrict__ images, const float* __restrict__ offset1,
                         const float* __restrict__ w1, const float* __restrict__ w2,
                         const float* __restrict__ w3a, const float* __restrict__ w3b,
                         const float* __restrict__ w3c, const float* __restrict__ w3d,
                         const float* __restrict__ w4, float* __restrict__ ws)
{
  const int idx = blockIdx.x * blockDim.x + threadIdx.x;
  const int stride = gridDim.x * blockDim.x;
  for (int i = idx; i < 1280; i += stride) ws[i] = 0.f;
  // padded volume 36^3, interior = images, border(2) = 0
  for (int i = idx; i < 46656; i += stride) {
    int x = i % 36, t = i / 36, y = t % 36, z = t / 36;
    int xo = x - 2, yo = y - 2, zo = z - 2;
    float val = 0.f;
    if ((unsigned)xo < 32u && (unsigned)yo < 32u && (unsigned)zo < 32u)
      val = images[(zo * 32 + yo) * 32 + xo];
    ws[OFF_PVOL + i] = val;
  }
  // tap params per k: shifts(+2 pad offset) + weights (sample b zy-weights negated)
  for (int k = idx; k < 1024; k += stride) {
    int*   tpi = reinterpret_cast<int*>(ws + OFF_TPAR) + (k << 5);
    float* tpf = ws + OFF_TPAR + (k << 5);
    int dxi[2], dyi[2], dzi[2]; float wx0[2], wx1[2], zz[2][4];
    for (int s = 0; s < 2; ++s) {
      float ox = offset1[k * 6 + s * 3 + 0] * 16.f;
      float oy = offset1[k * 6 + s * 3 + 1] * 16.f;
      float oz = offset1[k * 6 + s * 3 + 2] * 16.f;
      ox = fminf(fmaxf(ox, -100.f), 100.f);
      oy = fminf(fmaxf(oy, -100.f), 100.f);
      oz = fminf(fmaxf(oz, -100.f), 100.f);
      float fxf = floorf(ox), fyf = floorf(oy), fzf = floorf(oz);
      float fx = ox - fxf, fy = oy - fyf, fz = oz - fzf;
      dxi[s] = (int)fxf + 2; dyi[s] = (int)fyf + 2; dzi[s] = (int)fzf + 2;
      wx0[s] = 1.f - fx; wx1[s] = fx;
      float wy0 = 1.f - fy, wy1 = fy, wz0 = 1.f - fz, wz1 = fz;
      float sgn = s ? -1.f : 1.f;
      zz[s][0] = sgn * wz0 * wy0; zz[s][1] = sgn * wz0 * wy1;
      zz[s][2] = sgn * wz1 * wy0; zz[s][3] = sgn * wz1 * wy1;
    }
    tpi[0] = dxi[0]; tpi[1] = dyi[0]; tpi[2] = dzi[0]; tpi[3] = dxi[1];
    tpi[4] = dyi[1]; tpi[5] = dzi[1]; tpi[6] = 0; tpi[7] = 0;
    tpf[8]  = wx0[0]; tpf[9]  = wx1[0]; tpf[10] = zz[0][0]; tpf[11] = zz[0][1];
    tpf[12] = zz[0][2]; tpf[13] = zz[0][3]; tpf[14] = wx0[1]; tpf[15] = wx1[1];
    tpf[16] = zz[1][0]; tpf[17] = zz[1][1]; tpf[18] = zz[1][2]; tpf[19] = zz[1][3];
  }
  // weight transposes (contiguous in output channel for float4 loads)
  for (int i = idx; i < 65536; i += stride) {
    int o = i & 63, t = i >> 6, c = t & 255, gg = t >> 8;
    ws[OFF_W1T + i] = w1[gg * 16384 + o * 256 + c];
  }
  for (int i = idx; i < 32768; i += stride) { int o = i & 127, c = i >> 7; ws[OFF_W2T + i] = w2[o * 256 + c]; }
  for (int i = idx; i < 4096;  i += stride) { int o = i & 31,  c = i >> 5; ws[OFF_W3AT + i] = w3a[o * 128 + c]; }
  for (int i = idx; i < 5120;  i += stride) { int o = i & 31,  c = i >> 5; ws[OFF_W3BT + i] = w3b[o * 160 + c]; }
  for (int i = idx; i < 6144;  i += stride) { int o = i & 31,  c = i >> 5; ws[OFF_W3CT + i] = w3c[o * 192 + c]; }
  for (int i = idx; i < 7168;  i += stride) { int o = i & 31,  c = i >> 5; ws[OFF_W3DT + i] = w3d[o * 224 + c]; }
  for (int i = idx; i < 2048;  i += stride) { int l = i & 7,   c = i >> 3; ws[OFF_W4T + i] = w4[l * 256 + c]; }
}

// ---------------- S1: fused gather + grouped GEMM (y = w1 @ x) ----------------
__global__ __launch_bounds__(512) void s1_gather_gemm(
    const float* __restrict__ pvol, const int* __restrict__ tpar,
    const float* __restrict__ w1t, float* __restrict__ y, float* __restrict__ stats_y)
{
  const int tid = threadIdx.x;
  const int g = blockIdx.x >> 6;       // 0..3
  const int tile = blockIdx.x & 63;    // 0..63
  const int v = tile * 512 + tid;
  const int xv = v & 31, yv = (v >> 5) & 31, zv = v >> 10;
  float acc[64];
  #pragma unroll
  for (int o = 0; o < 64; ++o) acc[o] = 0.f;
  const int kbase = g << 8;
  for (int kl = 0; kl < 256; ++kl) {
    const int* tp = tpar + ((kbase + kl) << 5);
    int4 ia = *(const int4*)(tp);
    int4 ib = *(const int4*)(tp + 4);
    float4 fa = *(const float4*)((const float*)tp + 8);
    float4 fb = *(const float4*)((const float*)tp + 12);
    float4 fc = *(const float4*)((const float*)tp + 16);
    float xval;
    {
      int xc = min(max(xv + ia.x, 0), 34);
      int yc = min(max(yv + ia.y, 0), 34);
      int zc = min(max(zv + ia.z, 0), 34);
      int r0 = (zc * 36 + yc) * 36 + xc;
      float v00 = pvol[r0],        v01 = pvol[r0 + 1];
      float v10 = pvol[r0 + 36],   v11 = pvol[r0 + 37];
      float v20 = pvol[r0 + 1296], v21 = pvol[r0 + 1297];
      float v30 = pvol[r0 + 1332], v31 = pvol[r0 + 1333];
      float h00 = v00 * fa.x + v01 * fa.y, h01 = v10 * fa.x + v11 * fa.y;
      float h10 = v20 * fa.x + v21 * fa.y, h11 = v30 * fa.x + v31 * fa.y;
      xval = fa.z * h00 + fa.w * h01 + fb.x * h10 + fb.y * h11;
    }
    {
      int xc = min(max(xv + ia.w, 0), 34);
      int yc = min(max(yv + ib.x, 0), 34);
      int zc = min(max(zv + ib.y, 0), 34);
      int r0 = (zc * 36 + yc) * 36 + xc;
      float v00 = pvol[r0],        v01 = pvol[r0 + 1];
      float v10 = pvol[r0 + 36],   v11 = pvol[r0 + 37];
      float v20 = pvol[r0 + 1296], v21 = pvol[r0 + 1297];
      float v30 = pvol[r0 + 1332], v31 = pvol[r0 + 1333];
      float h00 = v00 * fb.z + v01 * fb.w, h01 = v10 * fb.z + v11 * fb.w;
      float h10 = v20 * fb.z + v21 * fb.w, h11 = v30 * fb.z + v31 * fb.w;
      xval += fc.x * h00 + fc.y * h01 + fc.z * h10 + fc.w * h11; // fc pre-negated
    }
    const float4* wk4 = (const float4*)(w1t + ((size_t)(kbase + kl) << 6));
    #pragma unroll
    for (int oq = 0; oq < 16; ++oq) {
      float4 w = wk4[oq];
      acc[oq * 4 + 0] = fmaf(w.x, xval, acc[oq * 4 + 0]);
      acc[oq * 4 + 1] = fmaf(w.y, xval, acc[oq * 4 + 1]);
      acc[oq * 4 + 2] = fmaf(w.z, xval, acc[oq * 4 + 2]);
      acc[oq * 4 + 3] = fmaf(w.w, xval, acc[oq * 4 + 3]);
    }
  }
  const int lane = tid & 63;
  #pragma unroll 1
  for (int o = 0; o < 64; ++o)
    y[((size_t)((g << 6) + o)) * VOXN + v] = acc[o];
  #pragma unroll 1
  for (int o = 0; o < 64; ++o) {
    float s = acc[o], q = acc[o] * acc[o];
    #pragma unroll
    for (int m = 32; m; m >>= 1) { s += __shfl_xor(s, m, 64); q += __shfl_xor(q, m, 64); }
    if (lane == 0) { atomicAdd(&stats_y[(g << 6) + o], s); atomicAdd(&stats_y[256 + (g << 6) + o], q); }
  }
}

// ---------------- S2: x1 = relu(BN(y)); x2pre = w2 @ x1 ----------------
__global__ __launch_bounds__(256) void s2_bn_gemm(
    const float* __restrict__ y, const float* __restrict__ stats_y,
    const float* __restrict__ g1, const float* __restrict__ b1,
    const float* __restrict__ w2t, float* __restrict__ x2p, float* __restrict__ stats_x2p)
{
  __shared__ float As[256], Bs[256];
  const int tid = threadIdx.x;
  {
    float m = stats_y[tid] * (1.f / VOXN);
    float vv = stats_y[256 + tid] * (1.f / VOXN) - m * m;
    float a = g1[tid] * rsqrtf(vv + 1e-5f);
    As[tid] = a; Bs[tid] = b1[tid] - m * a;
  }
  __syncthreads();
  const int half = blockIdx.y;
  const int n = blockIdx.x * 256 + tid;
  float acc[64];
  #pragma unroll
  for (int o = 0; o < 64; ++o) acc[o] = 0.f;
  for (int c = 0; c < 256; ++c) {
    float t = fmaxf(fmaf(y[(size_t)c * VOXN + n], As[c], Bs[c]), 0.f);
    const float4* wk4 = (const float4*)(w2t + c * 128 + half * 64);
    #pragma unroll
    for (int oq = 0; oq < 16; ++oq) {
      float4 w = wk4[oq];
      acc[oq * 4 + 0] = fmaf(w.x, t, acc[oq * 4 + 0]);
      acc[oq * 4 + 1] = fmaf(w.y, t, acc[oq * 4 + 1]);
      acc[oq * 4 + 2] = fmaf(w.z, t, acc[oq * 4 + 2]);
      acc[oq * 4 + 3] = fmaf(w.w, t, acc[oq * 4 + 3]);
    }
  }
  const int lane = tid & 63;
  #pragma unroll 1
  for (int o = 0; o < 64; ++o) x2p[((size_t)(half * 64 + o)) * VOXN + n] = acc[o];
  #pragma unroll 1
  for (int o = 0; o < 64; ++o) {
    float s = acc[o], q = acc[o] * acc[o];
    #pragma unroll
    for (int m = 32; m; m >>= 1) { s += __shfl_xor(s, m, 64); q += __shfl_xor(q, m, 64); }
    if (lane == 0) { atomicAdd(&stats_x2p[half * 64 + o], s); atomicAdd(&stats_x2p[128 + half * 64 + o], q); }
  }
}

// ---------------- S3: x2 = BN(x2pre) -> H[0:128]; h_a = relu(w3a@x2) -> H[128:160] ----------------
__global__ __launch_bounds__(256) void s3_x2_ha(
    const float* __restrict__ x2p, const float* __restrict__ stats_x2p,
    const float* __restrict__ g2, const float* __restrict__ b2,
    const float* __restrict__ w3at, float* __restrict__ H, float* __restrict__ stats_H)
{
  __shared__ float As[128], Bs[128];
  const int tid = threadIdx.x;
  if (tid < 128) {
    float m = stats_x2p[tid] * (1.f / VOXN);
    float vv = stats_x2p[128 + tid] * (1.f / VOXN) - m * m;
    float a = g2[tid] * rsqrtf(vv + 1e-5f);
    As[tid] = a; Bs[tid] = b2[tid] - m * a;
    if (blockIdx.x == 0) {
      // exact stats of x2 = a*x2pre + (b2 - m*a): mean = b2, var = a^2 * v
      float mean = b2[tid];
      float var = a * a * vv;
      stats_H[tid] = mean * (float)VOXN;
      stats_H[256 + tid] = (var + mean * mean) * (float)VOXN;
    }
  }
  __syncthreads();
  const int n = blockIdx.x * 256 + tid;
  float acc[32];
  #pragma unroll
  for (int o = 0; o < 32; ++o) acc[o] = 0.f;
  for (int c = 0; c < 128; ++c) {
    float x2v = fmaf(x2p[(size_t)c * VOXN + n], As[c], Bs[c]);
    H[(size_t)c * VOXN + n] = x2v;
    const float4* wk4 = (const float4*)(w3at + c * 32);
    #pragma unroll
    for (int oq = 0; oq < 8; ++oq) {
      float4 w = wk4[oq];
      acc[oq * 4 + 0] = fmaf(w.x, x2v, acc[oq * 4 + 0]);
      acc[oq * 4 + 1] = fmaf(w.y, x2v, acc[oq * 4 + 1]);
      acc[oq * 4 + 2] = fmaf(w.z, x2v, acc[oq * 4 + 2]);
      acc[oq * 4 + 3] = fmaf(w.w, x2v, acc[oq * 4 + 3]);
    }
  }
  const int lane = tid & 63;
  #pragma unroll 1
  for (int o = 0; o < 32; ++o) {
    float h = fmaxf(acc[o], 0.f); acc[o] = h;
    H[((size_t)(128 + o)) * VOXN + n] = h;
  }
  #pragma unroll 1
  for (int o = 0; o < 32; ++o) {
    float s = acc[o], q = acc[o] * acc[o];
    #pragma unroll
    for (int m = 32; m; m >>= 1) { s += __shfl_xor(s, m, 64); q += __shfl_xor(q, m, 64); }
    if (lane == 0) { atomicAdd(&stats_H[128 + o], s); atomicAdd(&stats_H[256 + 128 + o], q); }
  }
}

// ---------------- S4/5/6: h = relu(w @ BN(H[0:CIN])) -> H[och:och+32] ----------------
template<int CIN>
__global__ __launch_bounds__(256) void s_dense(
    const float* __restrict__ Hin, const float* __restrict__ stats_H,
    const float* __restrict__ g, const float* __restrict__ b,
    const float* __restrict__ wt, float* __restrict__ H, float* __restrict__ stats_out, int och)
{
  __shared__ float As[CIN], Bs[CIN];
  const int tid = threadIdx.x;
  if (tid < CIN) {
    float m = stats_H[tid] * (1.f / VOXN);
    float vv = stats_H[256 + tid] * (1.f / VOXN) - m * m;
    float a = g[tid] * rsqrtf(vv + 1e-5f);
    As[tid] = a; Bs[tid] = b[tid] - m * a;
  }
  __syncthreads();
  const int n = blockIdx.x * 256 + tid;
  float acc[32];
  #pragma unroll
  for (int o = 0; o < 32; ++o) acc[o] = 0.f;
  for (int c = 0; c < CIN; ++c) {
    float t = fmaf(Hin[(size_t)c * VOXN + n], As[c], Bs[c]);
    const float4* wk4 = (const float4*)(wt + c * 32);
    #pragma unroll
    for (int oq = 0; oq < 8; ++oq) {
      float4 w = wk4[oq];
      acc[oq * 4 + 0] = fmaf(w.x, t, acc[oq * 4 + 0]);
      acc[oq * 4 + 1] = fmaf(w.y, t, acc[oq * 4 + 1]);
      acc[oq * 4 + 2] = fmaf(w.z, t, acc[oq * 4 + 2]);
      acc[oq * 4 + 3] = fmaf(w.w, t, acc[oq * 4 + 3]);
    }
  }
  const int lane = tid & 63;
  #pragma unroll 1
  for (int o = 0; o < 32; ++o) {
    float h = fmaxf(acc[o], 0.f); acc[o] = h;
    H[((size_t)(och + o)) * VOXN + n] = h;
  }
  #pragma unroll 1
  for (int o = 0; o < 32; ++o) {
    float s = acc[o], q = acc[o] * acc[o];
    #pragma unroll
    for (int m = 32; m; m >>= 1) { s += __shfl_xor(s, m, 64); q += __shfl_xor(q, m, 64); }
    if (lane == 0) { atomicAdd(&stats_out[och + o], s); atomicAdd(&stats_out[256 + och + o], q); }
  }
}

// ---------------- S7: out = sigmoid(w4 @ BN(H) + b4) ----------------
__global__ __launch_bounds__(256) void s7_final(
    const float* __restrict__ H, const float* __restrict__ stats_H,
    const float* __restrict__ g3d, const float* __restrict__ b3d,
    const float* __restrict__ w4t, const float* __restrict__ b4, float* __restrict__ out)
{
  __shared__ float As[256], Bs[256];
  const int tid = threadIdx.x;
  {
    float m = stats_H[tid] * (1.f / VOXN);
    float vv = stats_H[256 + tid] * (1.f / VOXN) - m * m;
    float a = g3d[tid] * rsqrtf(vv + 1e-5f);
    As[tid] = a; Bs[tid] = b3d[tid] - m * a;
  }
  __syncthreads();
  const int n = blockIdx.x * 256 + tid;
  float acc[8];
  #pragma unroll
  for (int l = 0; l < 8; ++l) acc[l] = 0.f;
  for (int c = 0; c < 256; ++c) {
    float t = fmaf(H[(size_t)c * VOXN + n], As[c], Bs[c]);
    const float4* wk4 = (const float4*)(w4t + c * 8);
    float4 w0 = wk4[0], w1v = wk4[1];
    acc[0] = fmaf(w0.x, t, acc[0]);  acc[1] = fmaf(w0.y, t, acc[1]);
    acc[2] = fmaf(w0.z, t, acc[2]);  acc[3] = fmaf(w0.w, t, acc[3]);
    acc[4] = fmaf(w1v.x, t, acc[4]); acc[5] = fmaf(w1v.y, t, acc[5]);
    acc[6] = fmaf(w1v.z, t, acc[6]); acc[7] = fmaf(w1v.w, t, acc[7]);
  }
  #pragma unroll
  for (int l = 0; l < 8; ++l) {
    float xv = acc[l] + b4[l];
    out[(size_t)l * VOXN + n] = 1.f / (1.f + expf(-xv));
  }
}

extern "C" void kernel_launch(void* const* d_in, const int* in_sizes, int n_in,
                              void* d_out, int out_size, void* d_ws, size_t ws_size,
                              hipStream_t stream)
{
  const float* images  = (const float*)d_in[0];
  const float* offset1 = (const float*)d_in[1];
  const float* w1  = (const float*)d_in[2];
  const float* g1  = (const float*)d_in[3];
  const float* b1  = (const float*)d_in[4];
  const float* w2  = (const float*)d_in[5];
  const float* g2  = (const float*)d_in[6];
  const float* b2  = (const float*)d_in[7];
  const float* w3a = (const float*)d_in[8];
  const float* w3b = (const float*)d_in[9];
  const float* w3c = (const float*)d_in[10];
  const float* w3d = (const float*)d_in[11];
  const float* g3a = (const float*)d_in[12];
  const float* b3a = (const float*)d_in[13];
  const float* g3b = (const float*)d_in[14];
  const float* b3b = (const float*)d_in[15];
  const float* g3c = (const float*)d_in[16];
  const float* b3c = (const float*)d_in[17];
  const float* g3d = (const float*)d_in[18];
  const float* b3d = (const float*)d_in[19];
  const float* w4  = (const float*)d_in[20];
  const float* b4  = (const float*)d_in[21];

  float* ws  = (float*)d_ws;
  float* out = (float*)d_out;

  float* statsY = ws + OFF_STATS_Y;
  float* statsX = ws + OFF_STATS_X2P;
  float* statsH = ws + OFF_STATS_H;
  float* pvol   = ws + OFF_PVOL;
  float* w1t    = ws + OFF_W1T;
  float* w2t    = ws + OFF_W2T;
  float* YH     = ws + OFF_YH;   // y, later H
  float* x2p    = ws + OFF_X2P;

  s0_setup<<<dim3(64), dim3(256), 0, stream>>>(images, offset1, w1, w2, w3a, w3b, w3c, w3d, w4, ws);
  s1_gather_gemm<<<dim3(256), dim3(512), 0, stream>>>(pvol, (const int*)(ws + OFF_TPAR), w1t, YH, statsY);
  s2_bn_gemm<<<dim3(128, 2), dim3(256), 0, stream>>>(YH, statsY, g1, b1, w2t, x2p, statsX);
  s3_x2_ha<<<dim3(128), dim3(256), 0, stream>>>(x2p, statsX, g2, b2, ws + OFF_W3AT, YH, statsH);
  s_dense<160><<<dim3(128), dim3(256), 0, stream>>>(YH, statsH, g3a, b3a, ws + OFF_W3BT, YH, statsH, 160);
  s_dense<192><<<dim3(128), dim3(256), 0, stream>>>(YH, statsH, g3b, b3b, ws + OFF_W3CT, YH, statsH, 192);
  s_dense<224><<<dim3(128), dim3(256), 0, stream>>>(YH, statsH, g3c, b3c, ws + OFF_W3DT, YH, statsH, 224);
  s7_final<<<dim3(128), dim3(256), 0, stream>>>(YH, statsH, g3d, b3d, ws + OFF_W4T, b4, out);
}

// Round 2
// 1326.285 us; speedup vs baseline: 1.4090x; 1.4090x over previous
//
#include <hip/hip_runtime.h>
#include <math.h>

#define VOXN 32768

// ---- workspace layout (float offsets) ----
constexpr int OFF_STATS_Y   = 0;        // 512  (sum[256], sumsq[256])
constexpr int OFF_STATS_X2P = 512;      // 256  (sum[128], sumsq[128])
constexpr int OFF_STATS_H   = 768;      // 512  (sum[256], sumsq[256])
constexpr int OFF_PVOL      = 1280;     // 46656 padded 36^3 volume
constexpr int OFF_TPAR      = 48000;    // 1024*32 words (int+float mixed)
constexpr int OFF_W1T       = 80768;    // 65536: w1t[g][c][o] = w1[g][o][c]
constexpr int OFF_W2T       = 146304;   // 32768: w2t[c][o]
constexpr int OFF_W3AT      = 179072;   // 4096
constexpr int OFF_W3BT      = 183168;   // 5120
constexpr int OFF_W3CT      = 188288;   // 6144
constexpr int OFF_W3DT      = 194432;   // 7168
constexpr int OFF_W4T       = 201600;   // 2048
constexpr int OFF_YH        = 203648;   // 8388608 (y, later reused as H)
constexpr int OFF_X2P       = 8592256;  // 4194304

// Fully-unrolled (static-index) wave reduce + atomic — keeps acc[] in VGPRs.
template<int NO>
__device__ __forceinline__ void reduce_atomic(const float (&acc)[NO], float* __restrict__ stats,
                                              int base, int sq_off, int lane)
{
  #pragma unroll
  for (int o = 0; o < NO; ++o) {
    float s = acc[o], q = acc[o] * acc[o];
    #pragma unroll
    for (int m = 32; m; m >>= 1) { s += __shfl_xor(s, m, 64); q += __shfl_xor(q, m, 64); }
    if (lane == 0) { atomicAdd(&stats[base + o], s); atomicAdd(&stats[sq_off + base + o], q); }
  }
}

// ---------------- S0: setup ----------------
__global__ void s0_setup(const float* __restrict__ images, const float* __restrict__ offset1,
                         const float* __restrict__ w1, const float* __restrict__ w2,
                         const float* __restrict__ w3a, const float* __restrict__ w3b,
                         const float* __restrict__ w3c, const float* __restrict__ w3d,
                         const float* __restrict__ w4, float* __restrict__ ws)
{
  const int idx = blockIdx.x * blockDim.x + threadIdx.x;
  const int stride = gridDim.x * blockDim.x;
  for (int i = idx; i < 1280; i += stride) ws[i] = 0.f;
  for (int i = idx; i < 46656; i += stride) {
    int x = i % 36, t = i / 36, y = t % 36, z = t / 36;
    int xo = x - 2, yo = y - 2, zo = z - 2;
    float val = 0.f;
    if ((unsigned)xo < 32u && (unsigned)yo < 32u && (unsigned)zo < 32u)
      val = images[(zo * 32 + yo) * 32 + xo];
    ws[OFF_PVOL + i] = val;
  }
  for (int k = idx; k < 1024; k += stride) {
    int*   tpi = reinterpret_cast<int*>(ws + OFF_TPAR) + (k << 5);
    float* tpf = ws + OFF_TPAR + (k << 5);
    int dxi[2], dyi[2], dzi[2]; float wx0[2], wx1[2], zz[2][4];
    for (int s = 0; s < 2; ++s) {
      float ox = offset1[k * 6 + s * 3 + 0] * 16.f;
      float oy = offset1[k * 6 + s * 3 + 1] * 16.f;
      float oz = offset1[k * 6 + s * 3 + 2] * 16.f;
      ox = fminf(fmaxf(ox, -100.f), 100.f);
      oy = fminf(fmaxf(oy, -100.f), 100.f);
      oz = fminf(fmaxf(oz, -100.f), 100.f);
      float fxf = floorf(ox), fyf = floorf(oy), fzf = floorf(oz);
      float fx = ox - fxf, fy = oy - fyf, fz = oz - fzf;
      dxi[s] = (int)fxf + 2; dyi[s] = (int)fyf + 2; dzi[s] = (int)fzf + 2;
      wx0[s] = 1.f - fx; wx1[s] = fx;
      float wy0 = 1.f - fy, wy1 = fy, wz0 = 1.f - fz, wz1 = fz;
      float sgn = s ? -1.f : 1.f;
      zz[s][0] = sgn * wz0 * wy0; zz[s][1] = sgn * wz0 * wy1;
      zz[s][2] = sgn * wz1 * wy0; zz[s][3] = sgn * wz1 * wy1;
    }
    tpi[0] = dxi[0]; tpi[1] = dyi[0]; tpi[2] = dzi[0]; tpi[3] = dxi[1];
    tpi[4] = dyi[1]; tpi[5] = dzi[1]; tpi[6] = 0; tpi[7] = 0;
    tpf[8]  = wx0[0]; tpf[9]  = wx1[0]; tpf[10] = zz[0][0]; tpf[11] = zz[0][1];
    tpf[12] = zz[0][2]; tpf[13] = zz[0][3]; tpf[14] = wx0[1]; tpf[15] = wx1[1];
    tpf[16] = zz[1][0]; tpf[17] = zz[1][1]; tpf[18] = zz[1][2]; tpf[19] = zz[1][3];
  }
  for (int i = idx; i < 65536; i += stride) {
    int o = i & 63, t = i >> 6, c = t & 255, gg = t >> 8;
    ws[OFF_W1T + i] = w1[gg * 16384 + o * 256 + c];
  }
  for (int i = idx; i < 32768; i += stride) { int o = i & 127, c = i >> 7; ws[OFF_W2T + i] = w2[o * 256 + c]; }
  for (int i = idx; i < 4096;  i += stride) { int o = i & 31,  c = i >> 5; ws[OFF_W3AT + i] = w3a[o * 128 + c]; }
  for (int i = idx; i < 5120;  i += stride) { int o = i & 31,  c = i >> 5; ws[OFF_W3BT + i] = w3b[o * 160 + c]; }
  for (int i = idx; i < 6144;  i += stride) { int o = i & 31,  c = i >> 5; ws[OFF_W3CT + i] = w3c[o * 192 + c]; }
  for (int i = idx; i < 7168;  i += stride) { int o = i & 31,  c = i >> 5; ws[OFF_W3DT + i] = w3d[o * 224 + c]; }
  for (int i = idx; i < 2048;  i += stride) { int l = i & 7,   c = i >> 3; ws[OFF_W4T + i] = w4[l * 256 + c]; }
}

// ---------------- S1: fused gather + grouped GEMM (y = w1 @ x) ----------------
__global__ __launch_bounds__(512) void s1_gather_gemm(
    const float* __restrict__ pvol, const int* __restrict__ tpar,
    const float* __restrict__ w1t, float* __restrict__ y, float* __restrict__ stats_y)
{
  const int tid = threadIdx.x;
  const int g = blockIdx.x >> 6;       // 0..3
  const int tile = blockIdx.x & 63;    // 0..63
  const int v = tile * 512 + tid;
  const int xv = v & 31, yv = (v >> 5) & 31, zv = v >> 10;
  float acc[64];
  #pragma unroll
  for (int o = 0; o < 64; ++o) acc[o] = 0.f;
  const int kbase = g << 8;
  for (int kl = 0; kl < 256; ++kl) {
    const int* tp = tpar + ((kbase + kl) << 5);
    int4 ia = *(const int4*)(tp);
    int4 ib = *(const int4*)(tp + 4);
    float4 fa = *(const float4*)((const float*)tp + 8);
    float4 fb = *(const float4*)((const float*)tp + 12);
    float4 fc = *(const float4*)((const float*)tp + 16);
    float xval;
    {
      int xc = min(max(xv + ia.x, 0), 34);
      int yc = min(max(yv + ia.y, 0), 34);
      int zc = min(max(zv + ia.z, 0), 34);
      int r0 = (zc * 36 + yc) * 36 + xc;
      float v00 = pvol[r0],        v01 = pvol[r0 + 1];
      float v10 = pvol[r0 + 36],   v11 = pvol[r0 + 37];
      float v20 = pvol[r0 + 1296], v21 = pvol[r0 + 1297];
      float v30 = pvol[r0 + 1332], v31 = pvol[r0 + 1333];
      float h00 = v00 * fa.x + v01 * fa.y, h01 = v10 * fa.x + v11 * fa.y;
      float h10 = v20 * fa.x + v21 * fa.y, h11 = v30 * fa.x + v31 * fa.y;
      xval = fa.z * h00 + fa.w * h01 + fb.x * h10 + fb.y * h11;
    }
    {
      int xc = min(max(xv + ia.w, 0), 34);
      int yc = min(max(yv + ib.x, 0), 34);
      int zc = min(max(zv + ib.y, 0), 34);
      int r0 = (zc * 36 + yc) * 36 + xc;
      float v00 = pvol[r0],        v01 = pvol[r0 + 1];
      float v10 = pvol[r0 + 36],   v11 = pvol[r0 + 37];
      float v20 = pvol[r0 + 1296], v21 = pvol[r0 + 1297];
      float v30 = pvol[r0 + 1332], v31 = pvol[r0 + 1333];
      float h00 = v00 * fb.z + v01 * fb.w, h01 = v10 * fb.z + v11 * fb.w;
      float h10 = v20 * fb.z + v21 * fb.w, h11 = v30 * fb.z + v31 * fb.w;
      xval += fc.x * h00 + fc.y * h01 + fc.z * h10 + fc.w * h11; // fc pre-negated
    }
    const float4* wk4 = (const float4*)(w1t + ((size_t)(kbase + kl) << 6));
    #pragma unroll
    for (int oq = 0; oq < 16; ++oq) {
      float4 w = wk4[oq];
      acc[oq * 4 + 0] = fmaf(w.x, xval, acc[oq * 4 + 0]);
      acc[oq * 4 + 1] = fmaf(w.y, xval, acc[oq * 4 + 1]);
      acc[oq * 4 + 2] = fmaf(w.z, xval, acc[oq * 4 + 2]);
      acc[oq * 4 + 3] = fmaf(w.w, xval, acc[oq * 4 + 3]);
    }
  }
  const int lane = tid & 63;
  #pragma unroll
  for (int o = 0; o < 64; ++o)
    y[((size_t)((g << 6) + o)) * VOXN + v] = acc[o];
  reduce_atomic<64>(acc, stats_y, g << 6, 256, lane);
}

// ---------------- S2: x1 = relu(BN(y)); x2pre = w2 @ x1 (quarter of outputs per block) ----------------
__global__ __launch_bounds__(256) void s2_bn_gemm(
    const float* __restrict__ y, const float* __restrict__ stats_y,
    const float* __restrict__ g1, const float* __restrict__ b1,
    const float* __restrict__ w2t, float* __restrict__ x2p, float* __restrict__ stats_x2p)
{
  __shared__ float As[256], Bs[256];
  const int tid = threadIdx.x;
  {
    float m = stats_y[tid] * (1.f / VOXN);
    float vv = stats_y[256 + tid] * (1.f / VOXN) - m * m;
    float a = g1[tid] * rsqrtf(vv + 1e-5f);
    As[tid] = a; Bs[tid] = b1[tid] - m * a;
  }
  __syncthreads();
  const int q = blockIdx.y;            // 0..3 -> outputs q*32..q*32+31
  const int n = blockIdx.x * 256 + tid;
  float acc[32];
  #pragma unroll
  for (int o = 0; o < 32; ++o) acc[o] = 0.f;
  for (int c = 0; c < 256; ++c) {
    float t = fmaxf(fmaf(y[(size_t)c * VOXN + n], As[c], Bs[c]), 0.f);
    const float4* wk4 = (const float4*)(w2t + c * 128 + q * 32);
    #pragma unroll
    for (int oq = 0; oq < 8; ++oq) {
      float4 w = wk4[oq];
      acc[oq * 4 + 0] = fmaf(w.x, t, acc[oq * 4 + 0]);
      acc[oq * 4 + 1] = fmaf(w.y, t, acc[oq * 4 + 1]);
      acc[oq * 4 + 2] = fmaf(w.z, t, acc[oq * 4 + 2]);
      acc[oq * 4 + 3] = fmaf(w.w, t, acc[oq * 4 + 3]);
    }
  }
  const int lane = tid & 63;
  #pragma unroll
  for (int o = 0; o < 32; ++o) x2p[((size_t)(q * 32 + o)) * VOXN + n] = acc[o];
  reduce_atomic<32>(acc, stats_x2p, q * 32, 128, lane);
}

// ---------------- S3: x2 = BN(x2pre) -> H[0:128]; h_a = relu(w3a@x2) -> H[128:160] ----------------
__global__ __launch_bounds__(256) void s3_x2_ha(
    const float* __restrict__ x2p, const float* __restrict__ stats_x2p,
    const float* __restrict__ g2, const float* __restrict__ b2,
    const float* __restrict__ w3at, float* __restrict__ H, float* __restrict__ stats_H)
{
  __shared__ float As[128], Bs[128];
  const int tid = threadIdx.x;
  if (tid < 128) {
    float m = stats_x2p[tid] * (1.f / VOXN);
    float vv = stats_x2p[128 + tid] * (1.f / VOXN) - m * m;
    float a = g2[tid] * rsqrtf(vv + 1e-5f);
    As[tid] = a; Bs[tid] = b2[tid] - m * a;
    if (blockIdx.x == 0) {
      float mean = b2[tid];
      float var = a * a * vv;
      stats_H[tid] = mean * (float)VOXN;
      stats_H[256 + tid] = (var + mean * mean) * (float)VOXN;
    }
  }
  __syncthreads();
  const int n = blockIdx.x * 256 + tid;
  float acc[32];
  #pragma unroll
  for (int o = 0; o < 32; ++o) acc[o] = 0.f;
  for (int c = 0; c < 128; ++c) {
    float x2v = fmaf(x2p[(size_t)c * VOXN + n], As[c], Bs[c]);
    H[(size_t)c * VOXN + n] = x2v;
    const float4* wk4 = (const float4*)(w3at + c * 32);
    #pragma unroll
    for (int oq = 0; oq < 8; ++oq) {
      float4 w = wk4[oq];
      acc[oq * 4 + 0] = fmaf(w.x, x2v, acc[oq * 4 + 0]);
      acc[oq * 4 + 1] = fmaf(w.y, x2v, acc[oq * 4 + 1]);
      acc[oq * 4 + 2] = fmaf(w.z, x2v, acc[oq * 4 + 2]);
      acc[oq * 4 + 3] = fmaf(w.w, x2v, acc[oq * 4 + 3]);
    }
  }
  const int lane = tid & 63;
  #pragma unroll
  for (int o = 0; o < 32; ++o) {
    float h = fmaxf(acc[o], 0.f); const_cast<float&>(acc[o]) = h;
    H[((size_t)(128 + o)) * VOXN + n] = h;
  }
  reduce_atomic<32>(acc, stats_H, 128, 256, lane);
}

// ---------------- S4/5/6: h = relu(w @ BN(H[0:CIN])) -> H[och+osub .. +16] ----------------
template<int CIN>
__global__ __launch_bounds__(256) void s_dense(
    const float* __restrict__ Hin, const float* __restrict__ stats_H,
    const float* __restrict__ g, const float* __restrict__ b,
    const float* __restrict__ wt, float* __restrict__ H, float* __restrict__ stats_out, int och)
{
  __shared__ float As[CIN], Bs[CIN];
  const int tid = threadIdx.x;
  if (tid < CIN) {
    float m = stats_H[tid] * (1.f / VOXN);
    float vv = stats_H[256 + tid] * (1.f / VOXN) - m * m;
    float a = g[tid] * rsqrtf(vv + 1e-5f);
    As[tid] = a; Bs[tid] = b[tid] - m * a;
  }
  __syncthreads();
  const int osub = blockIdx.y * 16;    // 0 or 16
  const int n = blockIdx.x * 256 + tid;
  float acc[16];
  #pragma unroll
  for (int o = 0; o < 16; ++o) acc[o] = 0.f;
  for (int c = 0; c < CIN; ++c) {
    float t = fmaf(Hin[(size_t)c * VOXN + n], As[c], Bs[c]);
    const float4* wk4 = (const float4*)(wt + c * 32 + osub);
    #pragma unroll
    for (int oq = 0; oq < 4; ++oq) {
      float4 w = wk4[oq];
      acc[oq * 4 + 0] = fmaf(w.x, t, acc[oq * 4 + 0]);
      acc[oq * 4 + 1] = fmaf(w.y, t, acc[oq * 4 + 1]);
      acc[oq * 4 + 2] = fmaf(w.z, t, acc[oq * 4 + 2]);
      acc[oq * 4 + 3] = fmaf(w.w, t, acc[oq * 4 + 3]);
    }
  }
  const int lane = tid & 63;
  #pragma unroll
  for (int o = 0; o < 16; ++o) {
    float h = fmaxf(acc[o], 0.f);
    acc[o] = h;
    H[((size_t)(och + osub + o)) * VOXN + n] = h;
  }
  reduce_atomic<16>(acc, stats_out, och + osub, 256, lane);
}

// ---------------- S7: out = sigmoid(w4 @ BN(H) + b4) ----------------
__global__ __launch_bounds__(256) void s7_final(
    const float* __restrict__ H, const float* __restrict__ stats_H,
    const float* __restrict__ g3d, const float* __restrict__ b3d,
    const float* __restrict__ w4t, const float* __restrict__ b4, float* __restrict__ out)
{
  __shared__ float As[256], Bs[256];
  const int tid = threadIdx.x;
  {
    float m = stats_H[tid] * (1.f / VOXN);
    float vv = stats_H[256 + tid] * (1.f / VOXN) - m * m;
    float a = g3d[tid] * rsqrtf(vv + 1e-5f);
    As[tid] = a; Bs[tid] = b3d[tid] - m * a;
  }
  __syncthreads();
  const int n = blockIdx.x * 256 + tid;
  float acc[8];
  #pragma unroll
  for (int l = 0; l < 8; ++l) acc[l] = 0.f;
  for (int c = 0; c < 256; ++c) {
    float t = fmaf(H[(size_t)c * VOXN + n], As[c], Bs[c]);
    const float4* wk4 = (const float4*)(w4t + c * 8);
    float4 w0 = wk4[0], w1v = wk4[1];
    acc[0] = fmaf(w0.x, t, acc[0]);  acc[1] = fmaf(w0.y, t, acc[1]);
    acc[2] = fmaf(w0.z, t, acc[2]);  acc[3] = fmaf(w0.w, t, acc[3]);
    acc[4] = fmaf(w1v.x, t, acc[4]); acc[5] = fmaf(w1v.y, t, acc[5]);
    acc[6] = fmaf(w1v.z, t, acc[6]); acc[7] = fmaf(w1v.w, t, acc[7]);
  }
  #pragma unroll
  for (int l = 0; l < 8; ++l) {
    float xv = acc[l] + b4[l];
    out[(size_t)l * VOXN + n] = 1.f / (1.f + expf(-xv));
  }
}

extern "C" void kernel_launch(void* const* d_in, const int* in_sizes, int n_in,
                              void* d_out, int out_size, void* d_ws, size_t ws_size,
                              hipStream_t stream)
{
  const float* images  = (const float*)d_in[0];
  const float* offset1 = (const float*)d_in[1];
  const float* w1  = (const float*)d_in[2];
  const float* g1  = (const float*)d_in[3];
  const float* b1  = (const float*)d_in[4];
  const float* w2  = (const float*)d_in[5];
  const float* g2  = (const float*)d_in[6];
  const float* b2  = (const float*)d_in[7];
  const float* w3a = (const float*)d_in[8];
  const float* w3b = (const float*)d_in[9];
  const float* w3c = (const float*)d_in[10];
  const float* w3d = (const float*)d_in[11];
  const float* g3a = (const float*)d_in[12];
  const float* b3a = (const float*)d_in[13];
  const float* g3b = (const float*)d_in[14];
  const float* b3b = (const float*)d_in[15];
  const float* g3c = (const float*)d_in[16];
  const float* b3c = (const float*)d_in[17];
  const float* g3d = (const float*)d_in[18];
  const float* b3d = (const float*)d_in[19];
  const float* w4  = (const float*)d_in[20];
  const float* b4  = (const float*)d_in[21];

  float* ws  = (float*)d_ws;
  float* out = (float*)d_out;

  float* statsY = ws + OFF_STATS_Y;
  float* statsX = ws + OFF_STATS_X2P;
  float* statsH = ws + OFF_STATS_H;
  float* pvol   = ws + OFF_PVOL;
  float* w1t    = ws + OFF_W1T;
  float* w2t    = ws + OFF_W2T;
  float* YH     = ws + OFF_YH;   // y, later H
  float* x2p    = ws + OFF_X2P;

  s0_setup<<<dim3(64), dim3(256), 0, stream>>>(images, offset1, w1, w2, w3a, w3b, w3c, w3d, w4, ws);
  s1_gather_gemm<<<dim3(256), dim3(512), 0, stream>>>(pvol, (const int*)(ws + OFF_TPAR), w1t, YH, statsY);
  s2_bn_gemm<<<dim3(128, 4), dim3(256), 0, stream>>>(YH, statsY, g1, b1, w2t, x2p, statsX);
  s3_x2_ha<<<dim3(128), dim3(256), 0, stream>>>(x2p, statsX, g2, b2, ws + OFF_W3AT, YH, statsH);
  s_dense<160><<<dim3(128, 2), dim3(256), 0, stream>>>(YH, statsH, g3a, b3a, ws + OFF_W3BT, YH, statsH, 160);
  s_dense<192><<<dim3(128, 2), dim3(256), 0, stream>>>(YH, statsH, g3b, b3b, ws + OFF_W3CT, YH, statsH, 192);
  s_dense<224><<<dim3(128, 2), dim3(256), 0, stream>>>(YH, statsH, g3c, b3c, ws + OFF_W3DT, YH, statsH, 224);
  s7_final<<<dim3(128), dim3(256), 0, stream>>>(YH, statsH, g3d, b3d, ws + OFF_W4T, b4, out);
}